// Round 1
// baseline (1012.863 us; speedup 1.0000x reference)
//
#include <hip/hip_runtime.h>
#include <math.h>

// Problem constants (from setup_inputs): B=4, C=256 split into G=4 groups of C4=64.
#define BATCH 4
#define GRP   4
#define C4c   64
#define Hs    128
#define Ws    128
#define HWs   (Hs*Ws)      // 16384

// workspace layout (floats):
//   om  : [16 img][27][HW]          img = g*4 + b
//   wT  : [4 g][576 ck][64 o]       ck = c*9 + (ki*3+kj)
#define OM_ELEMS (16*27*HWs)

// ---------------------------------------------------------------------------
// Kernel T: transpose deform weights w[g][o][c][3][3] -> wT[g][ck][o]
// ---------------------------------------------------------------------------
__global__ void k_transpose_w(const float* __restrict__ w, float* __restrict__ wT) {
    int idx = blockIdx.x * 256 + threadIdx.x;       // idx = (g*576 + ck)*64 + o
    if (idx >= 4 * 576 * 64) return;
    int g = idx / 36864;
    int r = idx - g * 36864;
    int ck = r >> 6;
    int o  = r & 63;
    wT[idx] = w[(g * 64 + o) * 576 + ck];
}

// ---------------------------------------------------------------------------
// Kernel 1: offset/mask conv3x3 (C4=64 in, 27 out) + bias + sigmoid(mask)
// 16x16 pixel tile per WG, x patch staged in LDS in 16-channel chunks.
// ---------------------------------------------------------------------------
__global__ __launch_bounds__(256) void k_offconv(const float* __restrict__ x,
                                                 const float* __restrict__ w_om,
                                                 const float* __restrict__ b_om,
                                                 float* __restrict__ om) {
    const int img = blockIdx.y;          // g*4 + bb
    const int g = img >> 2, bb = img & 3;
    const int tile = blockIdx.x;         // 8x8 tiles of 16x16
    const int h0 = (tile >> 3) << 4;
    const int w0 = (tile & 7) << 4;
    const int tid = threadIdx.x;
    const int ty = tid >> 4, tx = tid & 15;

    __shared__ float patch[16 * 18 * 18];   // 20.7 KB

    float acc[27];
#pragma unroll
    for (int j = 0; j < 27; ++j) acc[j] = 0.f;

    const float* xg = x + (size_t)(bb * 256 + g * 64) * HWs;

#pragma unroll 1
    for (int cc = 0; cc < 4; ++cc) {
        __syncthreads();
        for (int i = tid; i < 16 * 18 * 18; i += 256) {
            int c = i / 324;
            int r = i - c * 324;
            int py = r / 18;
            int px = r - py * 18;
            int gh = h0 + py - 1, gw = w0 + px - 1;
            float v = 0.f;
            if (gh >= 0 && gh < Hs && gw >= 0 && gw < Ws)
                v = xg[(cc * 16 + c) * HWs + gh * Ws + gw];
            patch[i] = v;
        }
        __syncthreads();
#pragma unroll 1
        for (int c = 0; c < 16; ++c) {
            float xv[9];
#pragma unroll
            for (int di = 0; di < 3; ++di)
#pragma unroll
                for (int dj = 0; dj < 3; ++dj)
                    xv[di * 3 + dj] = patch[c * 324 + (ty + di) * 18 + (tx + dj)];
            // wave-uniform weight addresses -> scalar loads
            const float* wp = w_om + g * 27 * 576 + (cc * 16 + c) * 9;
#pragma unroll
            for (int j = 0; j < 27; ++j) {
#pragma unroll
                for (int k = 0; k < 9; ++k)
                    acc[j] = fmaf(xv[k], wp[j * 576 + k], acc[j]);
            }
        }
    }

    const int p = (h0 + ty) * Ws + (w0 + tx);
    float* omp = om + (size_t)img * 27 * HWs + p;
#pragma unroll
    for (int j = 0; j < 27; ++j) {
        float v = acc[j] + b_om[g * 27 + j];
        if (j >= 18) v = 1.f / (1.f + __expf(-v));   // mask = sigmoid
        omp[j * HWs] = v;
    }
}

// ---------------------------------------------------------------------------
// Kernel 2: modulated deformable conv (im2col-in-LDS GEMM) + bias + BN + SiLU
// WG = 256 threads, one (img, 64-pixel row segment). 8 chunks of 8 channels.
// ---------------------------------------------------------------------------
__global__ __launch_bounds__(256) void k_deform(const float* __restrict__ x,
                                                const float* __restrict__ om,
                                                const float* __restrict__ wT,
                                                const float* __restrict__ bias,
                                                const float* __restrict__ gamma,
                                                const float* __restrict__ beta,
                                                const float* __restrict__ mean,
                                                const float* __restrict__ var,
                                                float* __restrict__ out) {
    const int img = blockIdx.y;          // g*4 + bb
    const int g = img >> 2, bb = img & 3;
    const int p0 = blockIdx.x * 64;
    const int tid = threadIdx.x;

    __shared__ int4   prmO[576];                     // 9.2 KB: clamped gather offsets
    __shared__ float4 prmW[576];                     // 9.2 KB: mask-folded bilinear wts
    __shared__ __align__(16) float vsm[72 * 64];     // 18.4 KB: val[(c,k)][p] chunk

    const float* omg = om + (size_t)img * 27 * HWs;

    // ---- Phase A: bilinear params per (k, pixel), once per tile ----
    for (int idx = tid; idx < 576; idx += 256) {     // idx = k*64 + pp  (k wave-uniform)
        int k = idx >> 6, pp = idx & 63;
        int p = p0 + pp;
        int h = p >> 7, w = p & 127;
        float dy = omg[k * HWs + p];
        float dx = omg[(9 + k) * HWs + p];
        float m  = omg[(18 + k) * HWs + p];
        int ki = k / 3, kj = k - ki * 3;
        float py = (float)(h - 1 + ki) + dy;
        float px = (float)(w - 1 + kj) + dx;
        float fy = floorf(py), fx = floorf(px);
        float wy1 = py - fy, wx1 = px - fx;
        float wy0 = 1.f - wy1, wx0 = 1.f - wx1;
        int y0 = (int)fy, x0 = (int)fx;
        int y1 = y0 + 1, x1 = x0 + 1;
        bool vy0 = (y0 >= 0) && (y0 < Hs);
        bool vy1 = (y1 >= 0) && (y1 < Hs);
        bool vx0 = (x0 >= 0) && (x0 < Ws);
        bool vx1 = (x1 >= 0) && (x1 < Ws);
        int cy0 = min(max(y0, 0), Hs - 1), cy1 = min(max(y1, 0), Hs - 1);
        int cx0 = min(max(x0, 0), Ws - 1), cx1 = min(max(x1, 0), Ws - 1);
        prmO[idx] = make_int4(cy0 * Ws + cx0, cy0 * Ws + cx1,
                              cy1 * Ws + cx0, cy1 * Ws + cx1);
        prmW[idx] = make_float4(vy0 && vx0 ? wy0 * wx0 * m : 0.f,
                                vy0 && vx1 ? wy0 * wx1 * m : 0.f,
                                vy1 && vx0 ? wy1 * wx0 * m : 0.f,
                                vy1 && vx1 ? wy1 * wx1 * m : 0.f);
    }

    float acc[4][4];
#pragma unroll
    for (int a = 0; a < 4; ++a)
#pragma unroll
        for (int j = 0; j < 4; ++j) acc[a][j] = 0.f;

    const int pp = tid & 63;            // phase B: pixel
    const int kq = tid >> 6;            // phase B: which quarter of val rows
    const int psub = tid & 15;          // phase C: pixel quad
    const int oq   = tid >> 4;          // phase C: output quad
    const float* xg = x + (size_t)(bb * 256 + g * 64) * HWs;

#pragma unroll 1
    for (int cc = 0; cc < 8; ++cc) {
        __syncthreads();                // params ready / vsm free
        // ---- Phase B: gather val[(c,k) local 0..71][pixel] into LDS ----
#pragma unroll 1
        for (int i = 0; i < 18; ++i) {
            int v = i * 4 + kq;         // 0..71
            int c = v / 9;
            int k = v - c * 9;
            int4  off = prmO[k * 64 + pp];
            float4 wv = prmW[k * 64 + pp];
            const float* xc = xg + (cc * 8 + c) * HWs;
            float val = wv.x * xc[off.x] + wv.y * xc[off.y]
                      + wv.z * xc[off.z] + wv.w * xc[off.w];
            vsm[v * 64 + pp] = val;
        }
        __syncthreads();
        // ---- Phase C: register-tiled GEMM, 4 o x 4 p per thread ----
        const float* wTg = wT + (size_t)(g * 576 + cc * 72) * 64 + oq * 4;
#pragma unroll 4
        for (int v = 0; v < 72; ++v) {
            const float4 vals = *(const float4*)&vsm[v * 64 + psub * 4];
            const float4 wv   = *(const float4*)(wTg + v * 64);
            acc[0][0] = fmaf(wv.x, vals.x, acc[0][0]);
            acc[0][1] = fmaf(wv.x, vals.y, acc[0][1]);
            acc[0][2] = fmaf(wv.x, vals.z, acc[0][2]);
            acc[0][3] = fmaf(wv.x, vals.w, acc[0][3]);
            acc[1][0] = fmaf(wv.y, vals.x, acc[1][0]);
            acc[1][1] = fmaf(wv.y, vals.y, acc[1][1]);
            acc[1][2] = fmaf(wv.y, vals.z, acc[1][2]);
            acc[1][3] = fmaf(wv.y, vals.w, acc[1][3]);
            acc[2][0] = fmaf(wv.z, vals.x, acc[2][0]);
            acc[2][1] = fmaf(wv.z, vals.y, acc[2][1]);
            acc[2][2] = fmaf(wv.z, vals.z, acc[2][2]);
            acc[2][3] = fmaf(wv.z, vals.w, acc[2][3]);
            acc[3][0] = fmaf(wv.w, vals.x, acc[3][0]);
            acc[3][1] = fmaf(wv.w, vals.y, acc[3][1]);
            acc[3][2] = fmaf(wv.w, vals.z, acc[3][2]);
            acc[3][3] = fmaf(wv.w, vals.w, acc[3][3]);
        }
    }

    // ---- Epilogue: bias + BN + SiLU, float4 stores ----
    float* outg = out + (size_t)(bb * 256 + g * 64) * HWs;
#pragma unroll
    for (int a = 0; a < 4; ++a) {
        int o = oq * 4 + a;
        float bi = bias[g * 64 + o];
        float mu = mean[g * 64 + o];
        float sc = gamma[g * 64 + o] * rsqrtf(var[g * 64 + o] + 1e-5f);
        float be = beta[g * 64 + o];
        float4 r;
        {
            float y0 = (acc[a][0] + bi - mu) * sc + be;
            float y1 = (acc[a][1] + bi - mu) * sc + be;
            float y2 = (acc[a][2] + bi - mu) * sc + be;
            float y3 = (acc[a][3] + bi - mu) * sc + be;
            r.x = y0 / (1.f + __expf(-y0));
            r.y = y1 / (1.f + __expf(-y1));
            r.z = y2 / (1.f + __expf(-y2));
            r.w = y3 / (1.f + __expf(-y3));
        }
        *(float4*)&outg[(size_t)o * HWs + p0 + psub * 4] = r;
    }
}

// ---------------------------------------------------------------------------
extern "C" void kernel_launch(void* const* d_in, const int* in_sizes, int n_in,
                              void* d_out, int out_size, void* d_ws, size_t ws_size,
                              hipStream_t stream) {
    const float* x     = (const float*)d_in[0];
    const float* w     = (const float*)d_in[1];
    const float* b     = (const float*)d_in[2];
    const float* w_om  = (const float*)d_in[3];
    const float* b_om  = (const float*)d_in[4];
    const float* gamma = (const float*)d_in[5];
    const float* beta  = (const float*)d_in[6];
    const float* mean  = (const float*)d_in[7];
    const float* var   = (const float*)d_in[8];
    float* out = (float*)d_out;

    float* om = (float*)d_ws;                 // 16*27*16384 floats = 28.3 MB
    float* wT = om + OM_ELEMS;                // 4*576*64 floats   = 0.6 MB

    hipLaunchKernelGGL(k_transpose_w, dim3(576), dim3(256), 0, stream, w, wT);
    hipLaunchKernelGGL(k_offconv, dim3(64, 16), dim3(256), 0, stream,
                       x, w_om, b_om, om);
    hipLaunchKernelGGL(k_deform, dim3(256, 16), dim3(256), 0, stream,
                       x, om, wT, b, gamma, beta, mean, var, out);
}

// Round 3
// 301.101 us; speedup vs baseline: 3.3639x; 3.3639x over previous
//
#include <hip/hip_runtime.h>
#include <math.h>

// B=4, C=256 -> 4 groups x 64ch. H=W=128. img = g*4 + bb.
#define Hs 128
#define Ws 128
#define HWs 16384

typedef __attribute__((ext_vector_type(8))) short short8;
typedef __attribute__((ext_vector_type(8))) __bf16 bf16x8;
typedef __attribute__((ext_vector_type(4))) float f32x4;

static __device__ __forceinline__ float bf2f(unsigned short u) {
    union { unsigned int i; float f; } v; v.i = ((unsigned int)u) << 16; return v.f;
}
// round-to-nearest-even fp32 -> bf16 (finite inputs)
static __device__ __forceinline__ unsigned short f2bf(float f) {
    unsigned int u = __builtin_bit_cast(unsigned int, f);
    return (unsigned short)((u + 0x7fffu + ((u >> 16) & 1u)) >> 16);
}
static __device__ __forceinline__ unsigned int pack2bf(float a0, float a1) {
    return (unsigned int)f2bf(a0) | ((unsigned int)f2bf(a1) << 16);
}
static __device__ __forceinline__ f32x4 mfma16(short8 a, short8 b, f32x4 c) {
    return __builtin_amdgcn_mfma_f32_16x16x32_bf16(
        __builtin_bit_cast(bf16x8, a), __builtin_bit_cast(bf16x8, b), c, 0, 0, 0);
}

// ---------------------------------------------------------------------------
// P1: weight prep.
//  w2  [g][64 o][576 ck2] bf16, ck2 = k*64+c  (from w[g][o][c][9])
//  wom2[g][32 j][576 ck2] bf16 (j>=27 zero)   (from w_om[g][27][c][9])
//  scsh[0..255]=gamma*rsqrt(var+eps); scsh[256..511]=(b-mean)*sc+beta
// ---------------------------------------------------------------------------
__global__ void k_prep(const float* __restrict__ w, const float* __restrict__ b,
                       const float* __restrict__ w_om,
                       const float* __restrict__ gamma, const float* __restrict__ beta,
                       const float* __restrict__ mean, const float* __restrict__ var,
                       unsigned short* __restrict__ w2, unsigned short* __restrict__ wom2,
                       float* __restrict__ scsh) {
    int idx = blockIdx.x * 256 + threadIdx.x;
    if (idx < 4 * 64 * 576) {
        int go = idx / 576;
        int ck = idx - go * 576;
        int k = ck >> 6, c = ck & 63;
        w2[idx] = f2bf(w[go * 576 + c * 9 + k]);
    }
    if (idx < 4 * 32 * 576) {
        int gj = idx / 576;
        int g = gj >> 5, j = gj & 31;
        int ck = idx - gj * 576;
        int k = ck >> 6, c = ck & 63;
        float v = (j < 27) ? w_om[(g * 27 + j) * 576 + c * 9 + k] : 0.f;
        wom2[idx] = f2bf(v);
    }
    if (idx < 256) {
        float sc = gamma[idx] * rsqrtf(var[idx] + 1e-5f);
        scsh[idx] = sc;
        scsh[256 + idx] = (b[idx] - mean[idx]) * sc + beta[idx];
    }
}

// ---------------------------------------------------------------------------
// P2: x [bb][256ch][H][W] fp32 -> xT [img][H*W pixel][64 c] bf16 (channel-last)
// ---------------------------------------------------------------------------
__global__ __launch_bounds__(256) void k_xt(const float* __restrict__ x,
                                            unsigned short* __restrict__ xT) {
    const int img = blockIdx.y;
    const int g = img >> 2, bb = img & 3;
    const int p0 = blockIdx.x * 64;
    const int tid = threadIdx.x;
    __shared__ float t[64 * 65];

    const float* xg = x + (size_t)(bb * 256 + g * 64) * HWs + p0;
    const int pr = tid & 63, cw = tid >> 6;
#pragma unroll
    for (int i = 0; i < 16; ++i) {
        int c = i * 4 + cw;
        t[c * 65 + pr] = xg[(size_t)c * HWs + pr];
    }
    __syncthreads();
    const int p = tid >> 2, c16 = (tid & 3) * 16;
    unsigned short* dst = xT + (size_t)img * HWs * 64 + (size_t)(p0 + p) * 64 + c16;
    unsigned int rr[8];
#pragma unroll
    for (int q = 0; q < 8; ++q)
        rr[q] = pack2bf(t[(c16 + 2 * q) * 65 + p], t[(c16 + 2 * q + 1) * 65 + p]);
    *(uint4*)dst       = make_uint4(rr[0], rr[1], rr[2], rr[3]);
    *(uint4*)(dst + 8) = make_uint4(rr[4], rr[5], rr[6], rr[7]);
}

// ---------------------------------------------------------------------------
// Offset/mask conv as bf16 MFMA GEMM: om[img][27][HW] = wom2 (32x576) * patch
// Block: 64 pixels. 4 waves: wave = (nh<<1)|mt ; mt: j-tile, nh: pixel half.
// ---------------------------------------------------------------------------
__global__ __launch_bounds__(256, 3) void k_off(const unsigned short* __restrict__ xT,
                                                const unsigned short* __restrict__ wom2,
                                                const float* __restrict__ b_om,
                                                float* __restrict__ om) {
    const int img = blockIdx.y;
    const int g = img >> 2;
    const int p0 = blockIdx.x * 64;
    const int tid = threadIdx.x;
    const int lane = tid & 63, wv = tid >> 6;
    const int mt = wv & 1, nh = wv >> 1;
    const int m = lane & 15, q = lane >> 4;

    __shared__ unsigned short patch[64 * 72];

    short8 afrag[18];
    const unsigned short* wb = wom2 + (size_t)(g * 32 + mt * 16 + m) * 576 + q * 8;
#pragma unroll
    for (int t = 0; t < 18; ++t) afrag[t] = *(const short8*)(wb + t * 32);

    f32x4 acc[2];
    acc[0] = (f32x4){0.f, 0.f, 0.f, 0.f};
    acc[1] = (f32x4){0.f, 0.f, 0.f, 0.f};

    const unsigned short* xTi = xT + (size_t)img * HWs * 64;
    const int p = tid >> 2, c4 = tid & 3;
    const int hh0 = (p0 + p) >> 7, ww0 = (p0 + p) & 127;

#pragma unroll
    for (int k = 0; k < 9; ++k) {
        const int ki = k / 3, kj = k - ki * 3;
        const int hh = hh0 + ki - 1, ww = ww0 + kj - 1;
        const bool inb = (hh >= 0) && (hh < Hs) && (ww >= 0) && (ww < Ws);
        const unsigned short* src = xTi + (size_t)(hh * Ws + ww) * 64;
        __syncthreads();
#pragma unroll
        for (int it = 0; it < 2; ++it) {
            int oc8 = (c4 + it * 4) * 8;
            uint4 v = inb ? *(const uint4*)(src + oc8) : make_uint4(0, 0, 0, 0);
            *(uint4*)&patch[p * 72 + oc8] = v;
        }
        __syncthreads();
#pragma unroll
        for (int s = 0; s < 2; ++s) {
#pragma unroll
            for (int t2 = 0; t2 < 2; ++t2) {
                int pp = (nh * 2 + t2) * 16 + m;
                short8 bfrag = *(const short8*)&patch[pp * 72 + s * 32 + q * 8];
                acc[t2] = mfma16(afrag[k * 2 + s], bfrag, acc[t2]);
            }
        }
    }

    float* omi = om + (size_t)img * 27 * HWs + p0;
#pragma unroll
    for (int t2 = 0; t2 < 2; ++t2) {
#pragma unroll
        for (int r = 0; r < 4; ++r) {
            int j = mt * 16 + q * 4 + r;
            if (j < 27) {
                float v = acc[t2][r] + b_om[g * 27 + j];
                if (j >= 18) v = 1.f / (1.f + __expf(-v));  // mask sigmoid
                omi[(size_t)j * HWs + (nh * 2 + t2) * 16 + m] = v;
            }
        }
    }
}

// ---------------------------------------------------------------------------
// Deformable conv as bf16 MFMA GEMM + BN + SiLU.
// Block: 64 pixels, M=64 o, K=576 (9 chunks of 64: one 3x3 tap x 64 ch).
// Wave wv owns o-tile wv (16 o) x all 64 pixels (4 n-tiles).
// ---------------------------------------------------------------------------
__global__ __launch_bounds__(256, 3) void k_def(const unsigned short* __restrict__ xT,
                                                const float* __restrict__ om,
                                                const unsigned short* __restrict__ w2,
                                                const float* __restrict__ scsh,
                                                float* __restrict__ out) {
    const int img = blockIdx.y;
    const int g = img >> 2, bb = img & 3;
    const int p0 = blockIdx.x * 64;
    const int tid = threadIdx.x;
    const int lane = tid & 63, wv = tid >> 6;
    const int m = lane & 15, q = lane >> 4;

    __shared__ int   pO[4][576];
    __shared__ float pW[4][576];
    __shared__ unsigned short val[64 * 72];
    __shared__ float lsc[64], lsh[64];

    if (tid < 64) {
        lsc[tid] = scsh[g * 64 + tid];
        lsh[tid] = scsh[256 + g * 64 + tid];
    }

    // ---- Phase A: bilinear gather params per (k, pixel) ----
    const float* omg = om + (size_t)img * 27 * HWs;
    for (int idx = tid; idx < 576; idx += 256) {
        int k = idx >> 6, pp = idx & 63;
        int p = p0 + pp;
        int h = p >> 7, w = p & 127;
        float dy = omg[k * HWs + p];
        float dx = omg[(9 + k) * HWs + p];
        float mk = omg[(18 + k) * HWs + p];
        int ki = k / 3, kj = k - ki * 3;
        float py = (float)(h - 1 + ki) + dy;
        float px = (float)(w - 1 + kj) + dx;
        float fy = floorf(py), fx = floorf(px);
        float wy1 = py - fy, wx1 = px - fx;
        float wy0 = 1.f - wy1, wx0 = 1.f - wx1;
        int y0 = (int)fy, x0 = (int)fx, y1 = y0 + 1, x1 = x0 + 1;
        bool vy0 = (y0 >= 0) && (y0 < Hs), vy1 = (y1 >= 0) && (y1 < Hs);
        bool vx0 = (x0 >= 0) && (x0 < Ws), vx1 = (x1 >= 0) && (x1 < Ws);
        int cy0 = min(max(y0, 0), Hs - 1), cy1 = min(max(y1, 0), Hs - 1);
        int cx0 = min(max(x0, 0), Ws - 1), cx1 = min(max(x1, 0), Ws - 1);
        pO[0][idx] = cy0 * Ws + cx0;
        pO[1][idx] = cy0 * Ws + cx1;
        pO[2][idx] = cy1 * Ws + cx0;
        pO[3][idx] = cy1 * Ws + cx1;
        pW[0][idx] = (vy0 && vx0) ? wy0 * wx0 * mk : 0.f;
        pW[1][idx] = (vy0 && vx1) ? wy0 * wx1 * mk : 0.f;
        pW[2][idx] = (vy1 && vx0) ? wy1 * wx0 * mk : 0.f;
        pW[3][idx] = (vy1 && vx1) ? wy1 * wx1 * mk : 0.f;
    }

    // ---- A fragments: this wave's 16 output channels, whole K=576 ----
    short8 afrag[18];
    const unsigned short* wb = w2 + (size_t)(g * 64 + wv * 16 + m) * 576 + q * 8;
#pragma unroll
    for (int t = 0; t < 18; ++t) afrag[t] = *(const short8*)(wb + t * 32);

    f32x4 acc[4];
#pragma unroll
    for (int t = 0; t < 4; ++t) acc[t] = (f32x4){0.f, 0.f, 0.f, 0.f};

    const unsigned short* xTi = xT + (size_t)img * HWs * 64;
    const int p = tid >> 2, c4 = tid & 3;

#pragma unroll
    for (int k = 0; k < 9; ++k) {
        __syncthreads();   // covers Phase A (k=0) and val-consumed (k>0)
        // ---- Phase B: gather 64 channels at tap k for this pixel ----
        const int kb = k * 64 + p;
        const int off0 = pO[0][kb], off1 = pO[1][kb], off2 = pO[2][kb], off3 = pO[3][kb];
        const float w0f = pW[0][kb], w1f = pW[1][kb], w2f = pW[2][kb], w3f = pW[3][kb];
        const unsigned short* s0 = xTi + (size_t)off0 * 64;
        const unsigned short* s1 = xTi + (size_t)off1 * 64;
        const unsigned short* s2 = xTi + (size_t)off2 * 64;
        const unsigned short* s3 = xTi + (size_t)off3 * 64;
#pragma unroll
        for (int it = 0; it < 2; ++it) {
            const int oc8 = (c4 + it * 4) * 8;
            short8 x0v = *(const short8*)(s0 + oc8);
            short8 x1v = *(const short8*)(s1 + oc8);
            short8 x2v = *(const short8*)(s2 + oc8);
            short8 x3v = *(const short8*)(s3 + oc8);
            unsigned int rr[4];
#pragma unroll
            for (int e = 0; e < 4; ++e) {
                float a0 = w0f * bf2f((unsigned short)x0v[2 * e])
                         + w1f * bf2f((unsigned short)x1v[2 * e])
                         + w2f * bf2f((unsigned short)x2v[2 * e])
                         + w3f * bf2f((unsigned short)x3v[2 * e]);
                float a1 = w0f * bf2f((unsigned short)x0v[2 * e + 1])
                         + w1f * bf2f((unsigned short)x1v[2 * e + 1])
                         + w2f * bf2f((unsigned short)x2v[2 * e + 1])
                         + w3f * bf2f((unsigned short)x3v[2 * e + 1]);
                rr[e] = pack2bf(a0, a1);
            }
            *(uint4*)&val[p * 72 + oc8] = make_uint4(rr[0], rr[1], rr[2], rr[3]);
        }
        __syncthreads();
        // ---- Phase C: MFMA over this 64-wide K chunk ----
#pragma unroll
        for (int s = 0; s < 2; ++s) {
#pragma unroll
            for (int t = 0; t < 4; ++t) {
                short8 bfrag = *(const short8*)&val[(t * 16 + m) * 72 + s * 32 + q * 8];
                acc[t] = mfma16(afrag[k * 2 + s], bfrag, acc[t]);
            }
        }
    }

    // ---- Epilogue: BN + SiLU, coalesced dword stores ----
    float* outg = out + ((size_t)bb * 256 + g * 64) * HWs + p0;
#pragma unroll
    for (int t = 0; t < 4; ++t) {
#pragma unroll
        for (int r = 0; r < 4; ++r) {
            int o = wv * 16 + q * 4 + r;
            float y = acc[t][r] * lsc[o] + lsh[o];
            outg[(size_t)o * HWs + t * 16 + m] = y / (1.f + __expf(-y));
        }
    }
}

// ---------------------------------------------------------------------------
extern "C" void kernel_launch(void* const* d_in, const int* in_sizes, int n_in,
                              void* d_out, int out_size, void* d_ws, size_t ws_size,
                              hipStream_t stream) {
    const float* x     = (const float*)d_in[0];
    const float* w     = (const float*)d_in[1];
    const float* b     = (const float*)d_in[2];
    const float* w_om  = (const float*)d_in[3];
    const float* b_om  = (const float*)d_in[4];
    const float* gamma = (const float*)d_in[5];
    const float* beta  = (const float*)d_in[6];
    const float* mean  = (const float*)d_in[7];
    const float* var   = (const float*)d_in[8];
    float* out = (float*)d_out;

    char* ws = (char*)d_ws;
    float* om            = (float*)ws;                              // 28,311,552 B
    unsigned short* xT   = (unsigned short*)(ws + 28311552);        // 33,554,432 B
    unsigned short* w2   = (unsigned short*)(ws + 61865984);        //    294,912 B
    unsigned short* wom2 = (unsigned short*)(ws + 62160896);        //    147,456 B
    float* scsh          = (float*)(ws + 62308352);                 //      2,048 B

    hipLaunchKernelGGL(k_prep, dim3(576), dim3(256), 0, stream,
                       w, b, w_om, gamma, beta, mean, var, w2, wom2, scsh);
    hipLaunchKernelGGL(k_xt, dim3(256, 16), dim3(256), 0, stream, x, xT);
    hipLaunchKernelGGL(k_off, dim3(256, 16), dim3(256), 0, stream, xT, wom2, b_om, om);
    hipLaunchKernelGGL(k_def, dim3(256, 16), dim3(256), 0, stream, xT, om, w2, scsh, out);
}

// Round 5
// 296.168 us; speedup vs baseline: 3.4199x; 1.0167x over previous
//
#include <hip/hip_runtime.h>
#include <math.h>

// B=4, C=256 -> 4 groups x 64ch. H=W=128. img = g*4 + bb.
#define Hs 128
#define Ws 128
#define HWs 16384

typedef __attribute__((ext_vector_type(8))) short short8;
typedef __attribute__((ext_vector_type(8))) __bf16 bf16x8;
typedef __attribute__((ext_vector_type(4))) float f32x4;

static __device__ __forceinline__ float bf2f(unsigned short u) {
    union { unsigned int i; float f; } v; v.i = ((unsigned int)u) << 16; return v.f;
}
// round-to-nearest-even fp32 -> bf16 (finite inputs)
static __device__ __forceinline__ unsigned short f2bf(float f) {
    unsigned int u = __builtin_bit_cast(unsigned int, f);
    return (unsigned short)((u + 0x7fffu + ((u >> 16) & 1u)) >> 16);
}
static __device__ __forceinline__ unsigned int pack2bf(float a0, float a1) {
    return (unsigned int)f2bf(a0) | ((unsigned int)f2bf(a1) << 16);
}
static __device__ __forceinline__ f32x4 mfma16(short8 a, short8 b, f32x4 c) {
    return __builtin_amdgcn_mfma_f32_16x16x32_bf16(
        __builtin_bit_cast(bf16x8, a), __builtin_bit_cast(bf16x8, b), c, 0, 0, 0);
}

// ---------------------------------------------------------------------------
// P1: weight prep.
//  w2  [g][64 o][576 ck2] bf16, ck2 = k*64+c  (from w[g][o][c][9])
//  wom2[g][32 j][576 ck2] bf16 (j>=27 zero)   (from w_om[g][27][c][9])
//  scsh[0..255]=gamma*rsqrt(var+eps); scsh[256..511]=(b-mean)*sc+beta
// ---------------------------------------------------------------------------
__global__ void k_prep(const float* __restrict__ w, const float* __restrict__ b,
                       const float* __restrict__ w_om,
                       const float* __restrict__ gamma, const float* __restrict__ beta,
                       const float* __restrict__ mean, const float* __restrict__ var,
                       unsigned short* __restrict__ w2, unsigned short* __restrict__ wom2,
                       float* __restrict__ scsh) {
    int idx = blockIdx.x * 256 + threadIdx.x;
    if (idx < 4 * 64 * 576) {
        int go = idx / 576;
        int ck = idx - go * 576;
        int k = ck >> 6, c = ck & 63;
        w2[idx] = f2bf(w[go * 576 + c * 9 + k]);
    }
    if (idx < 4 * 32 * 576) {
        int gj = idx / 576;
        int g = gj >> 5, j = gj & 31;
        int ck = idx - gj * 576;
        int k = ck >> 6, c = ck & 63;
        float v = (j < 27) ? w_om[(g * 27 + j) * 576 + c * 9 + k] : 0.f;
        wom2[idx] = f2bf(v);
    }
    if (idx < 256) {
        float sc = gamma[idx] * rsqrtf(var[idx] + 1e-5f);
        scsh[idx] = sc;
        scsh[256 + idx] = (b[idx] - mean[idx]) * sc + beta[idx];
    }
}

// ---------------------------------------------------------------------------
// P2: x [bb][256ch][H][W] fp32 -> xT [img][H*W pixel][64 c] bf16 (channel-last)
// ---------------------------------------------------------------------------
__global__ __launch_bounds__(256) void k_xt(const float* __restrict__ x,
                                            unsigned short* __restrict__ xT) {
    const int img = blockIdx.y;
    const int g = img >> 2, bb = img & 3;
    const int p0 = blockIdx.x * 64;
    const int tid = threadIdx.x;
    __shared__ float t[64 * 65];

    const float* xg = x + (size_t)(bb * 256 + g * 64) * HWs + p0;
    const int pr = tid & 63, cw = tid >> 6;
#pragma unroll
    for (int i = 0; i < 16; ++i) {
        int c = i * 4 + cw;
        t[c * 65 + pr] = xg[(size_t)c * HWs + pr];
    }
    __syncthreads();
    const int p = tid >> 2, c16 = (tid & 3) * 16;
    unsigned short* dst = xT + (size_t)img * HWs * 64 + (size_t)(p0 + p) * 64 + c16;
    unsigned int rr[8];
#pragma unroll
    for (int q = 0; q < 8; ++q)
        rr[q] = pack2bf(t[(c16 + 2 * q) * 65 + p], t[(c16 + 2 * q + 1) * 65 + p]);
    *(uint4*)dst       = make_uint4(rr[0], rr[1], rr[2], rr[3]);
    *(uint4*)(dst + 8) = make_uint4(rr[4], rr[5], rr[6], rr[7]);
}

// ---------------------------------------------------------------------------
// Offset/mask conv as bf16 MFMA GEMM, row-based LDS reuse.
// Block = one (img, row h). Stage rows h-1..h+1 (130px x 64ch, zero halo)
// into LDS once; all 9 taps read LDS. Wave wv: mt=wv&1 (16 j), nh=wv>>1
// (4 n-tiles of 16 pixels).
// ---------------------------------------------------------------------------
__global__ __launch_bounds__(256, 2) void k_off(const unsigned short* __restrict__ xT,
                                                const unsigned short* __restrict__ wom2,
                                                const float* __restrict__ b_om,
                                                float* __restrict__ om) {
    const int img = blockIdx.y;
    const int g = img >> 2;
    const int h = blockIdx.x;
    const int tid = threadIdx.x;
    const int lane = tid & 63, wv = tid >> 6;
    const int mt = wv & 1, nh = wv >> 1;
    const int m = lane & 15, q = lane >> 4;

    __shared__ unsigned short xrow[3 * 130 * 72];   // 56,160 B, stride-72 pad

    const unsigned short* xTi = xT + (size_t)img * HWs * 64;
    // stage 3 rows with halo (zero-pad out of range)
    for (int i = tid; i < 3 * 130 * 8; i += 256) {
        int rr = i / 1040;
        int rem = i - rr * 1040;
        int px = rem >> 3, j = rem & 7;
        int gh = h + rr - 1, gw = px - 1;
        uint4 v = make_uint4(0, 0, 0, 0);
        if (gh >= 0 && gh < Hs && gw >= 0 && gw < Ws)
            v = *(const uint4*)(xTi + (size_t)(gh * Ws + gw) * 64 + j * 8);
        *(uint4*)&xrow[(rr * 130 + px) * 72 + j * 8] = v;
    }

    // A fragments: this wave's 16 rows of wom2, whole K=576
    short8 afrag[18];
    const unsigned short* wb = wom2 + (size_t)(g * 32 + mt * 16 + m) * 576 + q * 8;
#pragma unroll
    for (int t = 0; t < 18; ++t) afrag[t] = *(const short8*)(wb + t * 32);

    f32x4 acc[4];
#pragma unroll
    for (int t = 0; t < 4; ++t) acc[t] = (f32x4){0.f, 0.f, 0.f, 0.f};

    __syncthreads();

#pragma unroll
    for (int k = 0; k < 9; ++k) {
        const int ki = k / 3, kj = k - ki * 3;
#pragma unroll
        for (int s = 0; s < 2; ++s) {
#pragma unroll
            for (int t = 0; t < 4; ++t) {
                int px = (nh * 4 + t) * 16 + m + kj;   // halo-shifted column
                short8 bfrag = *(const short8*)&xrow[(ki * 130 + px) * 72 + (s * 4 + q) * 8];
                acc[t] = mfma16(afrag[k * 2 + s], bfrag, acc[t]);
            }
        }
    }

    float* omi = om + (size_t)img * 27 * HWs + h * Ws;
#pragma unroll
    for (int t = 0; t < 4; ++t) {
#pragma unroll
        for (int r = 0; r < 4; ++r) {
            int j = mt * 16 + q * 4 + r;
            if (j < 27) {
                float v = acc[t][r] + b_om[g * 27 + j];
                if (j >= 18) v = 1.f / (1.f + __expf(-v));  // mask sigmoid
                omi[(size_t)j * HWs + (nh * 4 + t) * 16 + m] = v;
            }
        }
    }
}

// ---------------------------------------------------------------------------
// Deformable conv as bf16 MFMA GEMM + BN + SiLU.  (R3 known-good version)
// Block: 64 pixels, M=64 o, K=576 (9 chunks of 64: one 3x3 tap x 64 ch).
// Wave wv owns o-tile wv (16 o) x all 64 pixels (4 n-tiles).
// ---------------------------------------------------------------------------
__global__ __launch_bounds__(256, 3) void k_def(const unsigned short* __restrict__ xT,
                                                const float* __restrict__ om,
                                                const unsigned short* __restrict__ w2,
                                                const float* __restrict__ scsh,
                                                float* __restrict__ out) {
    const int img = blockIdx.y;
    const int g = img >> 2, bb = img & 3;
    const int p0 = blockIdx.x * 64;
    const int tid = threadIdx.x;
    const int lane = tid & 63, wv = tid >> 6;
    const int m = lane & 15, q = lane >> 4;

    __shared__ int   pO[4][576];
    __shared__ float pW[4][576];
    __shared__ unsigned short val[64 * 72];
    __shared__ float lsc[64], lsh[64];

    if (tid < 64) {
        lsc[tid] = scsh[g * 64 + tid];
        lsh[tid] = scsh[256 + g * 64 + tid];
    }

    // ---- Phase A: bilinear gather params per (k, pixel) ----
    const float* omg = om + (size_t)img * 27 * HWs;
    for (int idx = tid; idx < 576; idx += 256) {
        int k = idx >> 6, pp = idx & 63;
        int p = p0 + pp;
        int h = p >> 7, w = p & 127;
        float dy = omg[k * HWs + p];
        float dx = omg[(9 + k) * HWs + p];
        float mk = omg[(18 + k) * HWs + p];
        int ki = k / 3, kj = k - ki * 3;
        float py = (float)(h - 1 + ki) + dy;
        float px = (float)(w - 1 + kj) + dx;
        float fy = floorf(py), fx = floorf(px);
        float wy1 = py - fy, wx1 = px - fx;
        float wy0 = 1.f - wy1, wx0 = 1.f - wx1;
        int y0 = (int)fy, x0 = (int)fx, y1 = y0 + 1, x1 = x0 + 1;
        bool vy0 = (y0 >= 0) && (y0 < Hs), vy1 = (y1 >= 0) && (y1 < Hs);
        bool vx0 = (x0 >= 0) && (x0 < Ws), vx1 = (x1 >= 0) && (x1 < Ws);
        int cy0 = min(max(y0, 0), Hs - 1), cy1 = min(max(y1, 0), Hs - 1);
        int cx0 = min(max(x0, 0), Ws - 1), cx1 = min(max(x1, 0), Ws - 1);
        pO[0][idx] = cy0 * Ws + cx0;
        pO[1][idx] = cy0 * Ws + cx1;
        pO[2][idx] = cy1 * Ws + cx0;
        pO[3][idx] = cy1 * Ws + cx1;
        pW[0][idx] = (vy0 && vx0) ? wy0 * wx0 * mk : 0.f;
        pW[1][idx] = (vy0 && vx1) ? wy0 * wx1 * mk : 0.f;
        pW[2][idx] = (vy1 && vx0) ? wy1 * wx0 * mk : 0.f;
        pW[3][idx] = (vy1 && vx1) ? wy1 * wx1 * mk : 0.f;
    }

    // ---- A fragments: this wave's 16 output channels, whole K=576 ----
    short8 afrag[18];
    const unsigned short* wb = w2 + (size_t)(g * 64 + wv * 16 + m) * 576 + q * 8;
#pragma unroll
    for (int t = 0; t < 18; ++t) afrag[t] = *(const short8*)(wb + t * 32);

    f32x4 acc[4];
#pragma unroll
    for (int t = 0; t < 4; ++t) acc[t] = (f32x4){0.f, 0.f, 0.f, 0.f};

    const unsigned short* xTi = xT + (size_t)img * HWs * 64;
    const int p = tid >> 2, c4 = tid & 3;

#pragma unroll
    for (int k = 0; k < 9; ++k) {
        __syncthreads();   // covers Phase A (k=0) and val-consumed (k>0)
        // ---- Phase B: gather 64 channels at tap k for this pixel ----
        const int kb = k * 64 + p;
        const int off0 = pO[0][kb], off1 = pO[1][kb], off2 = pO[2][kb], off3 = pO[3][kb];
        const float w0f = pW[0][kb], w1f = pW[1][kb], w2f = pW[2][kb], w3f = pW[3][kb];
        const unsigned short* s0 = xTi + (size_t)off0 * 64;
        const unsigned short* s1 = xTi + (size_t)off1 * 64;
        const unsigned short* s2 = xTi + (size_t)off2 * 64;
        const unsigned short* s3 = xTi + (size_t)off3 * 64;
#pragma unroll
        for (int it = 0; it < 2; ++it) {
            const int oc8 = (c4 + it * 4) * 8;
            short8 x0v = *(const short8*)(s0 + oc8);
            short8 x1v = *(const short8*)(s1 + oc8);
            short8 x2v = *(const short8*)(s2 + oc8);
            short8 x3v = *(const short8*)(s3 + oc8);
            unsigned int rr[4];
#pragma unroll
            for (int e = 0; e < 4; ++e) {
                float a0 = w0f * bf2f((unsigned short)x0v[2 * e])
                         + w1f * bf2f((unsigned short)x1v[2 * e])
                         + w2f * bf2f((unsigned short)x2v[2 * e])
                         + w3f * bf2f((unsigned short)x3v[2 * e]);
                float a1 = w0f * bf2f((unsigned short)x0v[2 * e + 1])
                         + w1f * bf2f((unsigned short)x1v[2 * e + 1])
                         + w2f * bf2f((unsigned short)x2v[2 * e + 1])
                         + w3f * bf2f((unsigned short)x3v[2 * e + 1]);
                rr[e] = pack2bf(a0, a1);
            }
            *(uint4*)&val[p * 72 + oc8] = make_uint4(rr[0], rr[1], rr[2], rr[3]);
        }
        __syncthreads();
        // ---- Phase C: MFMA over this 64-wide K chunk ----
#pragma unroll
        for (int s = 0; s < 2; ++s) {
#pragma unroll
            for (int t = 0; t < 4; ++t) {
                short8 bfrag = *(const short8*)&val[(t * 16 + m) * 72 + s * 32 + q * 8];
                acc[t] = mfma16(afrag[k * 2 + s], bfrag, acc[t]);
            }
        }
    }

    // ---- Epilogue: BN + SiLU, coalesced dword stores ----
    float* outg = out + ((size_t)bb * 256 + g * 64) * HWs + p0;
#pragma unroll
    for (int t = 0; t < 4; ++t) {
#pragma unroll
        for (int r = 0; r < 4; ++r) {
            int o = wv * 16 + q * 4 + r;
            float y = acc[t][r] * lsc[o] + lsh[o];
            outg[(size_t)o * HWs + t * 16 + m] = y / (1.f + __expf(-y));
        }
    }
}

// ---------------------------------------------------------------------------
extern "C" void kernel_launch(void* const* d_in, const int* in_sizes, int n_in,
                              void* d_out, int out_size, void* d_ws, size_t ws_size,
                              hipStream_t stream) {
    const float* x     = (const float*)d_in[0];
    const float* w     = (const float*)d_in[1];
    const float* b     = (const float*)d_in[2];
    const float* w_om  = (const float*)d_in[3];
    const float* b_om  = (const float*)d_in[4];
    const float* gamma = (const float*)d_in[5];
    const float* beta  = (const float*)d_in[6];
    const float* mean  = (const float*)d_in[7];
    const float* var   = (const float*)d_in[8];
    float* out = (float*)d_out;

    char* ws = (char*)d_ws;
    float* om            = (float*)ws;                              // 28,311,552 B
    unsigned short* xT   = (unsigned short*)(ws + 28311552);        // 33,554,432 B
    unsigned short* w2   = (unsigned short*)(ws + 61865984);        //    294,912 B
    unsigned short* wom2 = (unsigned short*)(ws + 62160896);        //    147,456 B
    float* scsh          = (float*)(ws + 62308352);                 //      2,048 B

    hipLaunchKernelGGL(k_prep, dim3(576), dim3(256), 0, stream,
                       w, b, w_om, gamma, beta, mean, var, w2, wom2, scsh);
    hipLaunchKernelGGL(k_xt, dim3(256, 16), dim3(256), 0, stream, x, xT);
    hipLaunchKernelGGL(k_off, dim3(128, 16), dim3(256), 0, stream, xT, wom2, b_om, om);
    hipLaunchKernelGGL(k_def, dim3(256, 16), dim3(256), 0, stream, xT, om, w2, scsh, out);
}

// Round 6
// 269.737 us; speedup vs baseline: 3.7550x; 1.0980x over previous
//
#include <hip/hip_runtime.h>
#include <math.h>

// B=4, C=256 -> 4 groups x 64ch. H=W=128. img = g*4 + bb.
#define Hs 128
#define Ws 128
#define HWs 16384

typedef __attribute__((ext_vector_type(8))) short short8;
typedef __attribute__((ext_vector_type(8))) __bf16 bf16x8;
typedef __attribute__((ext_vector_type(4))) float f32x4;

static __device__ __forceinline__ float bf2f(unsigned short u) {
    union { unsigned int i; float f; } v; v.i = ((unsigned int)u) << 16; return v.f;
}
// round-to-nearest-even fp32 -> bf16 (finite inputs)
static __device__ __forceinline__ unsigned short f2bf(float f) {
    unsigned int u = __builtin_bit_cast(unsigned int, f);
    return (unsigned short)((u + 0x7fffu + ((u >> 16) & 1u)) >> 16);
}
static __device__ __forceinline__ unsigned int pack2bf(float a0, float a1) {
    return (unsigned int)f2bf(a0) | ((unsigned int)f2bf(a1) << 16);
}
static __device__ __forceinline__ f32x4 mfma16(short8 a, short8 b, f32x4 c) {
    return __builtin_amdgcn_mfma_f32_16x16x32_bf16(
        __builtin_bit_cast(bf16x8, a), __builtin_bit_cast(bf16x8, b), c, 0, 0, 0);
}

// ---------------------------------------------------------------------------
// k_xt: x [bb][256ch][H][W] fp32 -> xT [img][H*W pixel][64 c] bf16
// (channel-last), with weight-prep fused into the first 576 blocks.
//  w2  [g][64 o][576 ck2] bf16, ck2 = k*64+c
//  wom2[g][32 j][576 ck2] bf16 (j>=27 zero)
//  scsh[0..255]=gamma*rsqrt(var+eps); scsh[256..511]=(b-mean)*sc+beta
// Prep outputs are consumed only by LATER kernels -> ordering safe.
// ---------------------------------------------------------------------------
__global__ __launch_bounds__(256) void k_xt(const float* __restrict__ x,
                                            const float* __restrict__ w,
                                            const float* __restrict__ b,
                                            const float* __restrict__ w_om,
                                            const float* __restrict__ gamma,
                                            const float* __restrict__ beta,
                                            const float* __restrict__ mean,
                                            const float* __restrict__ var,
                                            unsigned short* __restrict__ xT,
                                            unsigned short* __restrict__ w2,
                                            unsigned short* __restrict__ wom2,
                                            float* __restrict__ scsh) {
    const int tid = threadIdx.x;
    // ---- fused prep (blocks 0..575 of the flattened grid) ----
    const int flatb = blockIdx.y * 256 + blockIdx.x;
    if (flatb < 576) {
        int idx = flatb * 256 + tid;
        if (idx < 4 * 64 * 576) {
            int go = idx / 576;
            int ck = idx - go * 576;
            int k = ck >> 6, c = ck & 63;
            w2[idx] = f2bf(w[go * 576 + c * 9 + k]);
        }
        if (idx < 4 * 32 * 576) {
            int gj = idx / 576;
            int g = gj >> 5, j = gj & 31;
            int ck = idx - gj * 576;
            int k = ck >> 6, c = ck & 63;
            float v = (j < 27) ? w_om[(g * 27 + j) * 576 + c * 9 + k] : 0.f;
            wom2[idx] = f2bf(v);
        }
        if (idx < 256) {
            float sc = gamma[idx] * rsqrtf(var[idx] + 1e-5f);
            scsh[idx] = sc;
            scsh[256 + idx] = (b[idx] - mean[idx]) * sc + beta[idx];
        }
    }

    // ---- transpose/convert ----
    const int img = blockIdx.y;
    const int g = img >> 2, bb = img & 3;
    const int p0 = blockIdx.x * 64;
    __shared__ float t[64 * 65];

    const float* xg = x + (size_t)(bb * 256 + g * 64) * HWs + p0;
    const int pr = tid & 63, cw = tid >> 6;
#pragma unroll
    for (int i = 0; i < 16; ++i) {
        int c = i * 4 + cw;
        t[c * 65 + pr] = xg[(size_t)c * HWs + pr];
    }
    __syncthreads();
    const int p = tid >> 2, c16 = (tid & 3) * 16;
    unsigned short* dst = xT + (size_t)img * HWs * 64 + (size_t)(p0 + p) * 64 + c16;
    unsigned int rr[8];
#pragma unroll
    for (int q = 0; q < 8; ++q)
        rr[q] = pack2bf(t[(c16 + 2 * q) * 65 + p], t[(c16 + 2 * q + 1) * 65 + p]);
    *(uint4*)dst       = make_uint4(rr[0], rr[1], rr[2], rr[3]);
    *(uint4*)(dst + 8) = make_uint4(rr[4], rr[5], rr[6], rr[7]);
}

// ---------------------------------------------------------------------------
// Offset/mask conv as bf16 MFMA GEMM, row-based LDS reuse. (R5 known-good)
// ---------------------------------------------------------------------------
__global__ __launch_bounds__(256, 2) void k_off(const unsigned short* __restrict__ xT,
                                                const unsigned short* __restrict__ wom2,
                                                const float* __restrict__ b_om,
                                                float* __restrict__ om) {
    const int img = blockIdx.y;
    const int g = img >> 2;
    const int h = blockIdx.x;
    const int tid = threadIdx.x;
    const int lane = tid & 63, wv = tid >> 6;
    const int mt = wv & 1, nh = wv >> 1;
    const int m = lane & 15, q = lane >> 4;

    __shared__ unsigned short xrow[3 * 130 * 72];   // 56,160 B, stride-72 pad

    const unsigned short* xTi = xT + (size_t)img * HWs * 64;
    for (int i = tid; i < 3 * 130 * 8; i += 256) {
        int rr = i / 1040;
        int rem = i - rr * 1040;
        int px = rem >> 3, j = rem & 7;
        int gh = h + rr - 1, gw = px - 1;
        uint4 v = make_uint4(0, 0, 0, 0);
        if (gh >= 0 && gh < Hs && gw >= 0 && gw < Ws)
            v = *(const uint4*)(xTi + (size_t)(gh * Ws + gw) * 64 + j * 8);
        *(uint4*)&xrow[(rr * 130 + px) * 72 + j * 8] = v;
    }

    short8 afrag[18];
    const unsigned short* wb = wom2 + (size_t)(g * 32 + mt * 16 + m) * 576 + q * 8;
#pragma unroll
    for (int t = 0; t < 18; ++t) afrag[t] = *(const short8*)(wb + t * 32);

    f32x4 acc[4];
#pragma unroll
    for (int t = 0; t < 4; ++t) acc[t] = (f32x4){0.f, 0.f, 0.f, 0.f};

    __syncthreads();

#pragma unroll
    for (int k = 0; k < 9; ++k) {
        const int ki = k / 3, kj = k - ki * 3;
#pragma unroll
        for (int s = 0; s < 2; ++s) {
#pragma unroll
            for (int t = 0; t < 4; ++t) {
                int px = (nh * 4 + t) * 16 + m + kj;   // halo-shifted column
                short8 bfrag = *(const short8*)&xrow[(ki * 130 + px) * 72 + (s * 4 + q) * 8];
                acc[t] = mfma16(afrag[k * 2 + s], bfrag, acc[t]);
            }
        }
    }

    float* omi = om + (size_t)img * 27 * HWs + h * Ws;
#pragma unroll
    for (int t = 0; t < 4; ++t) {
#pragma unroll
        for (int r = 0; r < 4; ++r) {
            int j = mt * 16 + q * 4 + r;
            if (j < 27) {
                float v = acc[t][r] + b_om[g * 27 + j];
                if (j >= 18) v = 1.f / (1.f + __expf(-v));  // mask sigmoid
                omi[(size_t)j * HWs + (nh * 4 + t) * 16 + m] = v;
            }
        }
    }
}

// ---------------------------------------------------------------------------
// Deformable conv as bf16 MFMA GEMM + BN + SiLU.
// R3 structure + ONE change: double-buffered val + register prefetch of the
// next tap's gathers (loads in flight across the single barrier per tap).
// Combine math, chunk layout, pack: textually R3 (bit-identical output).
// ---------------------------------------------------------------------------
__global__ __launch_bounds__(256, 3) void k_def(const unsigned short* __restrict__ xT,
                                                const float* __restrict__ om,
                                                const unsigned short* __restrict__ w2,
                                                const float* __restrict__ scsh,
                                                float* __restrict__ out) {
    const int img = blockIdx.y;
    const int g = img >> 2, bb = img & 3;
    const int p0 = blockIdx.x * 64;
    const int tid = threadIdx.x;
    const int lane = tid & 63, wv = tid >> 6;
    const int m = lane & 15, q = lane >> 4;

    __shared__ int   pO[4][576];
    __shared__ float pW[4][576];
    __shared__ unsigned short val[2][64 * 72];
    __shared__ float lsc[64], lsh[64];

    if (tid < 64) {
        lsc[tid] = scsh[g * 64 + tid];
        lsh[tid] = scsh[256 + g * 64 + tid];
    }

    // ---- Phase A: bilinear gather params per (k, pixel) ----
    const float* omg = om + (size_t)img * 27 * HWs;
    for (int idx = tid; idx < 576; idx += 256) {
        int k = idx >> 6, pp = idx & 63;
        int p = p0 + pp;
        int h = p >> 7, w = p & 127;
        float dy = omg[k * HWs + p];
        float dx = omg[(9 + k) * HWs + p];
        float mk = omg[(18 + k) * HWs + p];
        int ki = k / 3, kj = k - ki * 3;
        float py = (float)(h - 1 + ki) + dy;
        float px = (float)(w - 1 + kj) + dx;
        float fy = floorf(py), fx = floorf(px);
        float wy1 = py - fy, wx1 = px - fx;
        float wy0 = 1.f - wy1, wx0 = 1.f - wx1;
        int y0 = (int)fy, x0 = (int)fx, y1 = y0 + 1, x1 = x0 + 1;
        bool vy0 = (y0 >= 0) && (y0 < Hs), vy1 = (y1 >= 0) && (y1 < Hs);
        bool vx0 = (x0 >= 0) && (x0 < Ws), vx1 = (x1 >= 0) && (x1 < Ws);
        int cy0 = min(max(y0, 0), Hs - 1), cy1 = min(max(y1, 0), Hs - 1);
        int cx0 = min(max(x0, 0), Ws - 1), cx1 = min(max(x1, 0), Ws - 1);
        pO[0][idx] = cy0 * Ws + cx0;
        pO[1][idx] = cy0 * Ws + cx1;
        pO[2][idx] = cy1 * Ws + cx0;
        pO[3][idx] = cy1 * Ws + cx1;
        pW[0][idx] = (vy0 && vx0) ? wy0 * wx0 * mk : 0.f;
        pW[1][idx] = (vy0 && vx1) ? wy0 * wx1 * mk : 0.f;
        pW[2][idx] = (vy1 && vx0) ? wy1 * wx0 * mk : 0.f;
        pW[3][idx] = (vy1 && vx1) ? wy1 * wx1 * mk : 0.f;
    }

    // ---- A fragments: this wave's 16 output channels, whole K=576 ----
    short8 afrag[18];
    const unsigned short* wb = w2 + (size_t)(g * 64 + wv * 16 + m) * 576 + q * 8;
#pragma unroll
    for (int t = 0; t < 18; ++t) afrag[t] = *(const short8*)(wb + t * 32);

    f32x4 acc[4];
#pragma unroll
    for (int t = 0; t < 4; ++t) acc[t] = (f32x4){0.f, 0.f, 0.f, 0.f};

    const unsigned short* xTi = xT + (size_t)img * HWs * 64;
    const int p = tid >> 2, c4 = tid & 3;

    __syncthreads();   // Phase A (and lsc/lsh) visible

    // register prefetch: 8 chunks (4 corners x 2 channel-halves) + weights
    uint4 gth[8];
    float wf0, wf1, wf2, wf3;
    auto fetch = [&](int k) {
        const int kb = k * 64 + p;
        const int off0 = pO[0][kb], off1 = pO[1][kb], off2 = pO[2][kb], off3 = pO[3][kb];
        wf0 = pW[0][kb]; wf1 = pW[1][kb]; wf2 = pW[2][kb]; wf3 = pW[3][kb];
        const unsigned short* s0 = xTi + (size_t)off0 * 64;
        const unsigned short* s1 = xTi + (size_t)off1 * 64;
        const unsigned short* s2 = xTi + (size_t)off2 * 64;
        const unsigned short* s3 = xTi + (size_t)off3 * 64;
        gth[0] = *(const uint4*)(s0 + c4 * 8);
        gth[1] = *(const uint4*)(s1 + c4 * 8);
        gth[2] = *(const uint4*)(s2 + c4 * 8);
        gth[3] = *(const uint4*)(s3 + c4 * 8);
        gth[4] = *(const uint4*)(s0 + (c4 + 4) * 8);
        gth[5] = *(const uint4*)(s1 + (c4 + 4) * 8);
        gth[6] = *(const uint4*)(s2 + (c4 + 4) * 8);
        gth[7] = *(const uint4*)(s3 + (c4 + 4) * 8);
    };
    fetch(0);

#pragma unroll
    for (int k = 0; k < 9; ++k) {
        unsigned short* vb = &val[k & 1][0];
        // ---- combine (R3 scalar math on prefetched regs), natural layout ----
#pragma unroll
        for (int it = 0; it < 2; ++it) {
            const int oc8 = (c4 + it * 4) * 8;
            unsigned int rr[4];
#pragma unroll
            for (int e = 0; e < 4; ++e) {
                const unsigned int u0 = ((const unsigned int*)&gth[it * 4 + 0])[e];
                const unsigned int u1 = ((const unsigned int*)&gth[it * 4 + 1])[e];
                const unsigned int u2 = ((const unsigned int*)&gth[it * 4 + 2])[e];
                const unsigned int u3 = ((const unsigned int*)&gth[it * 4 + 3])[e];
                float a0 = wf0 * bf2f((unsigned short)(u0 & 0xffff))
                         + wf1 * bf2f((unsigned short)(u1 & 0xffff))
                         + wf2 * bf2f((unsigned short)(u2 & 0xffff))
                         + wf3 * bf2f((unsigned short)(u3 & 0xffff));
                float a1 = wf0 * bf2f((unsigned short)(u0 >> 16))
                         + wf1 * bf2f((unsigned short)(u1 >> 16))
                         + wf2 * bf2f((unsigned short)(u2 >> 16))
                         + wf3 * bf2f((unsigned short)(u3 >> 16));
                rr[e] = pack2bf(a0, a1);
            }
            *(uint4*)&vb[p * 72 + oc8] = make_uint4(rr[0], rr[1], rr[2], rr[3]);
        }
        if (k < 8) fetch(k + 1);   // next tap's loads in flight across barrier
        __syncthreads();
        // ---- Phase C: MFMA over this 64-wide K chunk (R3 layout) ----
        const unsigned short* vr = &val[k & 1][0];
#pragma unroll
        for (int s = 0; s < 2; ++s) {
#pragma unroll
            for (int t = 0; t < 4; ++t) {
                short8 bfrag = *(const short8*)&vr[(t * 16 + m) * 72 + s * 32 + q * 8];
                acc[t] = mfma16(afrag[k * 2 + s], bfrag, acc[t]);
            }
        }
    }

    // ---- Epilogue: BN + SiLU, coalesced dword stores ----
    float* outg = out + ((size_t)bb * 256 + g * 64) * HWs + p0;
#pragma unroll
    for (int t = 0; t < 4; ++t) {
#pragma unroll
        for (int r = 0; r < 4; ++r) {
            int o = wv * 16 + q * 4 + r;
            float y = acc[t][r] * lsc[o] + lsh[o];
            outg[(size_t)o * HWs + t * 16 + m] = y / (1.f + __expf(-y));
        }
    }
}

// ---------------------------------------------------------------------------
extern "C" void kernel_launch(void* const* d_in, const int* in_sizes, int n_in,
                              void* d_out, int out_size, void* d_ws, size_t ws_size,
                              hipStream_t stream) {
    const float* x     = (const float*)d_in[0];
    const float* w     = (const float*)d_in[1];
    const float* b     = (const float*)d_in[2];
    const float* w_om  = (const float*)d_in[3];
    const float* b_om  = (const float*)d_in[4];
    const float* gamma = (const float*)d_in[5];
    const float* beta  = (const float*)d_in[6];
    const float* mean  = (const float*)d_in[7];
    const float* var   = (const float*)d_in[8];
    float* out = (float*)d_out;

    char* ws = (char*)d_ws;
    float* om            = (float*)ws;                              // 28,311,552 B
    unsigned short* xT   = (unsigned short*)(ws + 28311552);        // 33,554,432 B
    unsigned short* w2   = (unsigned short*)(ws + 61865984);        //    294,912 B
    unsigned short* wom2 = (unsigned short*)(ws + 62160896);        //    147,456 B
    float* scsh          = (float*)(ws + 62308352);                 //      2,048 B

    hipLaunchKernelGGL(k_xt, dim3(256, 16), dim3(256), 0, stream,
                       x, w, b, w_om, gamma, beta, mean, var, xT, w2, wom2, scsh);
    hipLaunchKernelGGL(k_off, dim3(128, 16), dim3(256), 0, stream, xT, wom2, b_om, om);
    hipLaunchKernelGGL(k_def, dim3(256, 16), dim3(256), 0, stream, xT, om, w2, scsh, out);
}